// Round 6
// baseline (989.729 us; speedup 1.0000x reference)
//
#include <hip/hip_runtime.h>

// ConvLSTM2D (B=16,T=5,H=W=256,Cin=3,F=8) + BN + LeakyReLU + Dense(8->2)
// PERSISTENT kernel, manual grid barrier (atomic counters in d_ws; cooperative
// launch failed silently in round 5 -> zero output). 512 blocks x 2 tiles each
// (32x32 px), __launch_bounds__(256,3) -> >=768-block residency capacity,
// 1.5x margin over grid=512 -> no deadlock. c state in REGISTERS. h fp16
// ping-pong in global. Epilogue fused into t=4. Convs: fp16 MFMA 16x16x32,
// weights split hi/lo (z = xh*(wh+wl) + h*(wh+wl)); x hi-only.

#define BB  16
#define TT  5
#define HH  256
#define WW  256
#define CIN 3
#define FF  8
#define GG  32

#define TW  32   // tile width
#define THT 32   // tile height
#define LW  34   // TW+2 halo
#define LH  34   // THT+2 halo
#define NG  16   // 16x16-px groups per wave per tile
#define NBLK 512

typedef _Float16 half8 __attribute__((ext_vector_type(8)));
typedef _Float16 half4 __attribute__((ext_vector_type(4)));
typedef float    floatx4 __attribute__((ext_vector_type(4)));

__device__ __forceinline__ float frcp(float x) { return __builtin_amdgcn_rcpf(x); }
__device__ __forceinline__ float fsig(float x) { return frcp(1.0f + __expf(-x)); }
__device__ __forceinline__ float ftanh_(float x) { return 1.0f - 2.0f * frcp(1.0f + __expf(2.0f * x)); }

#define MFMA(A, B, C) __builtin_amdgcn_mfma_f32_16x16x32_f16((A), (B), (C), 0, 0, 0)

// ---------------------------------------------------------------------------
// Setup: 10 B-fragments x {hi, lo}. MFMA B layout: n = lane&15, k = quad*8+j.
// K-chunks: 0: x taps0-7 (k=tap*4+ci, ci padded to 4)
//           1: x tap8   (k=ci, only k<3 nonzero)
//           2..4: h taps [4c..4c+3] (k=(tap-4c)*8+ci), taps>8 zero
// ---------------------------------------------------------------------------
__global__ void build_frags(const float* __restrict__ wk,
                            const float* __restrict__ wr,
                            _Float16* __restrict__ blob) {
    const int lane = threadIdx.x & 63;
    const int quad = lane >> 4, nlo = lane & 15;
    for (int chunk = 0; chunk < 5; ++chunk) {
        for (int nh = 0; nh < 2; ++nh) {
            const int n = nh * 16 + nlo;
            const int frag = chunk * 2 + nh;
            _Float16* dhi = blob + ((size_t)frag * 64 + lane) * 8;
            _Float16* dlo = blob + ((size_t)(10 + frag) * 64 + lane) * 8;
            for (int j = 0; j < 8; ++j) {
                const int k = quad * 8 + j;
                float w = 0.0f;
                if (chunk == 0) {
                    int tap = k >> 2, ci = k & 3;
                    if (ci < 3) w = wk[(tap * 3 + ci) * GG + n];
                } else if (chunk == 1) {
                    if (quad == 0 && j < 3) w = wk[(8 * 3 + j) * GG + n];
                } else {
                    int c = chunk - 2;
                    int tap = c * 4 + quad, ci = j;
                    if (tap < 9) w = wr[(tap * FF + ci) * GG + n];
                }
                _Float16 wh = (_Float16)w;
                dhi[j] = wh;
                dlo[j] = (_Float16)(w - (float)wh);
            }
        }
    }
}

// ---------------------------------------------------------------------------
// Grid barrier: device-scope counter, one per step boundary (zeroed each call).
// ---------------------------------------------------------------------------
__device__ __forceinline__ void grid_barrier(unsigned* cnt) {
    __syncthreads();
    __threadfence();                       // release this block's h writes
    if (threadIdx.x == 0) {
        __hip_atomic_fetch_add(cnt, 1u, __ATOMIC_ACQ_REL, __HIP_MEMORY_SCOPE_AGENT);
        while (__hip_atomic_load(cnt, __ATOMIC_ACQUIRE, __HIP_MEMORY_SCOPE_AGENT)
               < (unsigned)NBLK)
            __builtin_amdgcn_s_sleep(8);
    }
    __syncthreads();
    __threadfence();                       // acquire remote h writes
}

// ---------------------------------------------------------------------------
// One 32x32 tile, one timestep. creg passed by reference (stays in VGPRs).
// ---------------------------------------------------------------------------
__device__ __forceinline__ void process_tile(
    int t, int tile,
    const float* __restrict__ xg,
    const half8 (&bfh)[10], const half8 (&bfl)[10],
    float bv0, float bv1,
    float bn_s, float bn_b, float dw0, float dw1, float db0, float db1,
    const _Float16* __restrict__ hin, _Float16* __restrict__ hout,
    float* __restrict__ out,
    half8* hls, half4* xls,
    float (&creg)[NG][2])
{
    const int tid  = threadIdx.x;
    const int b = tile >> 6, by = (tile >> 3) & 7, bx = tile & 7;
    const int lane = tid & 63, wave = tid >> 6;
    const int quad = lane >> 4, nlo = lane & 15;
    const bool lo8 = (nlo < 8);
    const int fc = nlo & 7;

    __syncthreads();   // previous tile's LDS readers done before restage

    // ---- stage x halo tile (fp32 -> fp16) ----
    for (int l = tid; l < LH * LW; l += 256) {
        int r = l / LW, c = l - r * LW;
        int gy = by * THT + r - 1, gx = bx * TW + c - 1;
        half4 vh = {(_Float16)0, (_Float16)0, (_Float16)0, (_Float16)0};
        if ((unsigned)gy < HH && (unsigned)gx < WW) {
            const float* p = xg + (((size_t)(b * TT + t) * HH + gy) * WW + gx) * CIN;
            vh.x = (_Float16)p[0]; vh.y = (_Float16)p[1]; vh.z = (_Float16)p[2];
        }
        xls[l] = vh;
    }
    // ---- stage h halo tile ----
    if (t > 0) {
        for (int l = tid; l < LH * LW; l += 256) {
            int r = l / LW, c = l - r * LW;
            int gy = by * THT + r - 1, gx = bx * TW + c - 1;
            half8 v = {(_Float16)0, (_Float16)0, (_Float16)0, (_Float16)0,
                       (_Float16)0, (_Float16)0, (_Float16)0, (_Float16)0};
            if ((unsigned)gy < HH && (unsigned)gx < WW)
                v = *(const half8*)(hin + ((size_t)(b * HH + gy) * WW + gx) * FF);
            hls[l] = v;
        }
    }
    __syncthreads();

#pragma unroll
    for (int g = 0; g < NG; ++g) {
        const int lr  = wave * 8 + (g >> 1);
        const int gx0 = (g & 1) * 16;
        const int lc  = gx0 + nlo;            // A-op: m = lane&15 -> pixel col

        const int t0 = 2 * quad, t1 = t0 + 1;
        half4 p = xls[(lr + t0 / 3) * LW + lc + t0 % 3];
        half4 q = xls[(lr + t1 / 3) * LW + lc + t1 % 3];
        half4 s = xls[(lr + 2) * LW + lc + 2];            // tap 8
        half8 a_xA = (half8){p.x, p.y, p.z, p.w, q.x, q.y, q.z, q.w};
        half8 a_xB = (half8){s.x, s.y, s.z, s.w, s.x, s.y, s.z, s.w};

        floatx4 acc0 = {bv0, bv0, bv0, bv0};
        floatx4 acc1 = {bv1, bv1, bv1, bv1};
        acc0 = MFMA(a_xA, bfh[0], acc0);  acc1 = MFMA(a_xA, bfh[1], acc1);
        acc0 = MFMA(a_xB, bfh[2], acc0);  acc1 = MFMA(a_xB, bfh[3], acc1);
        acc0 = MFMA(a_xA, bfl[0], acc0);  acc1 = MFMA(a_xA, bfl[1], acc1);
        acc0 = MFMA(a_xB, bfl[2], acc0);  acc1 = MFMA(a_xB, bfl[3], acc1);
        if (t > 0) {
#pragma unroll
            for (int c = 0; c < 3; ++c) {
                int tap = c * 4 + quad;
                if (tap > 8) tap = 8;          // padded taps: B rows zero
                half8 ah = hls[(lr + tap / 3) * LW + lc + tap % 3];
                acc0 = MFMA(ah, bfh[4 + c * 2], acc0);
                acc1 = MFMA(ah, bfh[5 + c * 2], acc1);
                acc0 = MFMA(ah, bfl[4 + c * 2], acc0);
                acc1 = MFMA(ah, bfl[5 + c * 2], acc1);
            }
        }

        // gate phase: C layout pixel m=quad*4+reg, ch=nlo / nlo+16.
        float s0 = lo8 ? acc0[2] : acc0[0]; float r0 = __shfl_xor(s0, 8, 64);
        float s1 = lo8 ? acc0[3] : acc0[1]; float r1 = __shfl_xor(s1, 8, 64);
        float s2 = lo8 ? acc1[2] : acc1[0]; float r2 = __shfl_xor(s2, 8, 64);
        float s3 = lo8 ? acc1[3] : acc1[1]; float r3 = __shfl_xor(s3, 8, 64);

        const float zi0 = lo8 ? acc0[0] : r0, zi1 = lo8 ? acc0[1] : r1;
        const float zf0 = lo8 ? r0 : acc0[2], zf1 = lo8 ? r1 : acc0[3];
        const float zg0 = lo8 ? acc1[0] : r2, zg1 = lo8 ? acc1[1] : r3;
        const float zo0 = lo8 ? r2 : acc1[2], zo1 = lo8 ? r3 : acc1[3];

        const float ii0 = fsig(zi0), ff0 = fsig(zf0), gg0 = ftanh_(zg0), oo0 = fsig(zo0);
        const float cn0 = ff0 * creg[g][0] + ii0 * gg0;
        const float hn0 = oo0 * ftanh_(cn0);
        const float ii1 = fsig(zi1), ff1 = fsig(zf1), gg1 = ftanh_(zg1), oo1 = fsig(zo1);
        const float cn1 = ff1 * creg[g][1] + ii1 * gg1;
        const float hn1 = oo1 * ftanh_(cn1);
        creg[g][0] = cn0; creg[g][1] = cn1;

        const int m0 = quad * 4 + (lo8 ? 0 : 2);
        const int gy = by * THT + lr;
        if (t < TT - 1) {
            _Float16* hp = hout + ((size_t)(b * HH + gy) * WW + bx * TW + gx0 + m0) * FF + fc;
            hp[0]  = (_Float16)hn0;
            hp[FF] = (_Float16)hn1;
        } else {
            // fused epilogue: BN -> LeakyReLU(0.3) -> Dense(8->2)
            float y0 = bn_s * hn0 + bn_b; y0 = (y0 >= 0.f) ? y0 : 0.3f * y0;
            float y1 = bn_s * hn1 + bn_b; y1 = (y1 >= 0.f) ? y1 : 0.3f * y1;
            float p00 = y0 * dw0, p01 = y0 * dw1;
            float p10 = y1 * dw0, p11 = y1 * dw1;
#pragma unroll
            for (int m = 1; m <= 4; m <<= 1) {
                p00 += __shfl_xor(p00, m, 64);
                p01 += __shfl_xor(p01, m, 64);
                p10 += __shfl_xor(p10, m, 64);
                p11 += __shfl_xor(p11, m, 64);
            }
            const int j = nlo & 7;
            if (j < 4) {
                const int px = m0 + (j >> 1);
                const int k  = j & 1;
                float val = (j == 0 ? p00 : j == 1 ? p01 : j == 2 ? p10 : p11)
                            + (k ? db1 : db0);
                out[((size_t)(b * HH + gy) * WW + bx * TW + gx0 + px) * 2 + k] = val;
            }
        }
    }
}

// ---------------------------------------------------------------------------
// Persistent ConvLSTM: 512 blocks x 256 thr, 2 tiles/block, manual grid sync.
// ---------------------------------------------------------------------------
__global__ __launch_bounds__(256, 3) void lstm_all(
    const float* __restrict__ xg,
    const _Float16* __restrict__ blob,
    const float* __restrict__ bias,
    const float* __restrict__ gamma, const float* __restrict__ beta,
    const float* __restrict__ mean,  const float* __restrict__ var,
    const float* __restrict__ dw,    const float* __restrict__ db,
    _Float16* __restrict__ h0g, _Float16* __restrict__ h1g,
    float* __restrict__ out, unsigned* __restrict__ barcnt)
{
    __shared__ half8 hls[LH * LW];
    __shared__ half4 xls[LH * LW];

    const int lane = threadIdx.x & 63;
    const int nlo = lane & 15, fc = nlo & 7;

    half8 bfh[10], bfl[10];
#pragma unroll
    for (int i = 0; i < 10; ++i) {
        bfh[i] = *(const half8*)(blob + ((size_t)i * 64 + lane) * 8);
        bfl[i] = *(const half8*)(blob + ((size_t)(10 + i) * 64 + lane) * 8);
    }
    const float bv0 = bias[nlo], bv1 = bias[16 + nlo];
    const float bn_s = gamma[fc] * rsqrtf(var[fc] + 1e-3f);
    const float bn_b = beta[fc] - mean[fc] * bn_s;
    const float dw0 = dw[fc * 2 + 0], dw1 = dw[fc * 2 + 1];
    const float db0 = db[0], db1 = db[1];

    float cregA[NG][2], cregB[NG][2];
#pragma unroll
    for (int g = 0; g < NG; ++g) {
        cregA[g][0] = 0.f; cregA[g][1] = 0.f;
        cregB[g][0] = 0.f; cregB[g][1] = 0.f;
    }

    for (int t = 0; t < TT; ++t) {
        const _Float16* hin = (t & 1) ? h0g : h1g;   // t=1 reads h0g, t=2 h1g, ...
        _Float16* hout      = (t & 1) ? h1g : h0g;   // t=0 writes h0g

        process_tile(t, (int)blockIdx.x, xg, bfh, bfl, bv0, bv1,
                     bn_s, bn_b, dw0, dw1, db0, db1,
                     hin, hout, out, hls, xls, cregA);
        process_tile(t, (int)blockIdx.x + NBLK, xg, bfh, bfl, bv0, bv1,
                     bn_s, bn_b, dw0, dw1, db0, db1,
                     hin, hout, out, hls, xls, cregB);

        if (t < TT - 1) grid_barrier(barcnt + t * 16);   // 64B-spaced counters
    }
}

extern "C" void kernel_launch(void* const* d_in, const int* in_sizes, int n_in,
                              void* d_out, int out_size, void* d_ws, size_t ws_size,
                              hipStream_t stream) {
    const float* x     = (const float*)d_in[0];
    const float* wk    = (const float*)d_in[1];
    const float* wr    = (const float*)d_in[2];
    const float* bias  = (const float*)d_in[3];
    const float* gamma = (const float*)d_in[4];
    const float* beta  = (const float*)d_in[5];
    const float* mean  = (const float*)d_in[6];
    const float* var   = (const float*)d_in[7];
    const float* dw    = (const float*)d_in[8];
    const float* db    = (const float*)d_in[9];
    float* out = (float*)d_out;

    // ws: blob 20KB @0 | barrier counters @24576 (256B) | h0 @32768 | h1
    const size_t state = (size_t)BB * HH * WW * FF;
    _Float16* blob   = (_Float16*)d_ws;
    unsigned* barcnt = (unsigned*)((char*)d_ws + 24576);
    _Float16* h0     = (_Float16*)((char*)d_ws + 32768);
    _Float16* h1     = (_Float16*)((char*)h0 + state * 2);

    hipMemsetAsync((char*)d_ws + 24576, 0, 256, stream);   // zero barrier counters
    build_frags<<<1, 64, 0, stream>>>(wk, wr, blob);

    lstm_all<<<dim3(NBLK), dim3(256), 0, stream>>>(
        x, blob, bias, gamma, beta, mean, var, dw, db, h0, h1, out, barcnt);
}

// Round 7
// 267.183 us; speedup vs baseline: 3.7043x; 3.7043x over previous
//
#include <hip/hip_runtime.h>

// ConvLSTM2D (B=16,T=5,H=W=256,Cin=3,F=8) + BN + LeakyReLU + Dense(8->2)
// Multi-launch (round-4 structure, validated 276us): one kernel per timestep,
// h fp16 ping-pong. Round-7 deltas: c state fp16 (halves c traffic), epilogue
// fused into t=4 (no h4 store, no epilogue kernel), x-lo MFMAs dropped
// (validated absmax-neutral), c prefetched before LDS staging, exp2 scale
// (-log2e / +2log2e) folded into weights+bias at build time.
// NOTE round-6 persistent kernel regressed 3.6x: VGPR cap spilled the weight
// fragments + c regs to scratch (84 VGPRs vs 144 needed; 600 MB scratch
// traffic, VALUBusy 0.5%). Do not revisit without a spill-free budget.

#define BB  16
#define TT  5
#define HH  256
#define WW  256
#define CIN 3
#define FF  8
#define GG  32

#define TW  32   // tile width (pixels)
#define THT 16   // tile height
#define LW  34   // TW+2 halo
#define LH  18   // THT+2 halo
#define NG  8    // 16x16-px groups per wave

#define LOG2E 1.44269504088896340736f

typedef _Float16 half8  __attribute__((ext_vector_type(8)));
typedef _Float16 half4  __attribute__((ext_vector_type(4)));
typedef _Float16 half2t __attribute__((ext_vector_type(2)));
typedef float    floatx4 __attribute__((ext_vector_type(4)));

__device__ __forceinline__ float frcp(float x) { return __builtin_amdgcn_rcpf(x); }
// z pre-scaled by -log2e:  sigmoid(z0) = 1/(1+2^z)
__device__ __forceinline__ float sig2(float z)  { return frcp(1.0f + __builtin_amdgcn_exp2f(z)); }
// z pre-scaled by +2log2e: tanh(z0) = 1 - 2/(1+2^z)
__device__ __forceinline__ float tanh2(float z) { return 1.0f - 2.0f * frcp(1.0f + __builtin_amdgcn_exp2f(z)); }

#define MFMA(A, B, C) __builtin_amdgcn_mfma_f32_16x16x32_f16((A), (B), (C), 0, 0, 0)

// ---------------------------------------------------------------------------
// Setup: 10 B-fragments x {hi, lo}, with per-column activation scale folded:
// cols 0..15 (i,f) and 24..31 (o): *(-log2e); cols 16..23 (g): *(+2log2e).
// MFMA B layout: n = lane&15, k = quad*8+j.
// K-chunks: 0: x taps0-7 (k=tap*4+ci, ci padded to 4)
//           1: x tap8   (k=ci, only k<3 nonzero)
//           2..4: h taps [4c..4c+3] (k=(tap-4c)*8+ci), taps>8 zero
// ---------------------------------------------------------------------------
__global__ void build_frags(const float* __restrict__ wk,
                            const float* __restrict__ wr,
                            _Float16* __restrict__ blob) {
    const int lane = threadIdx.x & 63;
    const int quad = lane >> 4, nlo = lane & 15;
    for (int chunk = 0; chunk < 5; ++chunk) {
        for (int nh = 0; nh < 2; ++nh) {
            const int n = nh * 16 + nlo;
            const float scale = (n >= 16 && n < 24) ? (2.0f * LOG2E) : (-LOG2E);
            const int frag = chunk * 2 + nh;
            _Float16* dhi = blob + ((size_t)frag * 64 + lane) * 8;
            _Float16* dlo = blob + ((size_t)(10 + frag) * 64 + lane) * 8;
            for (int j = 0; j < 8; ++j) {
                const int k = quad * 8 + j;
                float w = 0.0f;
                if (chunk == 0) {
                    int tap = k >> 2, ci = k & 3;
                    if (ci < 3) w = wk[(tap * 3 + ci) * GG + n];
                } else if (chunk == 1) {
                    if (quad == 0 && j < 3) w = wk[(8 * 3 + j) * GG + n];
                } else {
                    int c = chunk - 2;
                    int tap = c * 4 + quad, ci = j;
                    if (tap < 9) w = wr[(tap * FF + ci) * GG + n];
                }
                w *= scale;
                _Float16 wh = (_Float16)w;
                dhi[j] = wh;
                dlo[j] = (_Float16)(w - (float)wh);
            }
        }
    }
}

// ---------------------------------------------------------------------------
// One ConvLSTM timestep. MODE: 0=first (no h/c in), 1=mid, 2=last (+epilogue).
// Block = 256 thr (4 waves), tile 32x16 px; grid (8,16,16) = 2048 blocks.
// ---------------------------------------------------------------------------
template <int MODE>
__global__ __launch_bounds__(256) void lstm_step(
    const float* __restrict__ xg,       // [B,T,H,W,3] fp32
    int t,
    const _Float16* __restrict__ blob,  // scaled B-fragments (hi 0..9, lo 10..19)
    const float* __restrict__ bias,     // [32] (unscaled; scaled here)
    const _Float16* __restrict__ hin,   // h(t-1) fp16
    _Float16* __restrict__ hout,        // h(t) fp16
    _Float16* __restrict__ cbuf,        // c fp16, [group][lane]{2} custom layout
    const float* __restrict__ gamma, const float* __restrict__ beta,
    const float* __restrict__ mean,  const float* __restrict__ var,
    const float* __restrict__ dw,    const float* __restrict__ db,
    float* __restrict__ out)            // [B,H,W,2] (MODE 2 only)
{
    __shared__ half8 hls[LH * LW];     // h tile + halo
    __shared__ half4 xls[LH * LW];     // x tile + halo (3ch + pad)

    const int tid  = threadIdx.x;
    const int bx = blockIdx.x, by = blockIdx.y, b = blockIdx.z;
    const int lane = tid & 63, wave = tid >> 6;
    const int quad = lane >> 4, nlo = lane & 15;
    const bool lo8 = (nlo < 8);
    const int fc = nlo & 7;

    const int gidbase = (((b * (int)gridDim.y + by) * (int)gridDim.x + bx) * 4 + wave) * NG;

    // ---- prefetch c for all groups (in flight during LDS staging) ----
    half2t cpre[NG];
    if (MODE != 0) {
#pragma unroll
        for (int g = 0; g < NG; ++g)
            cpre[g] = ((const half2t*)cbuf)[(size_t)(gidbase + g) * 64 + lane];
    }

    // B-fragments (L1/L2-hot)
    half8 bfh[10], bfl[10];
#pragma unroll
    for (int i = 0; i < 10; ++i) {
        bfh[i] = *(const half8*)(blob + ((size_t)i * 64 + lane) * 8);
        bfl[i] = *(const half8*)(blob + ((size_t)(10 + i) * 64 + lane) * 8);
    }
    // bias, activation-scale folded (cols 16..23 are the g gate)
    const float bv0 = bias[nlo] * (-LOG2E);
    const float bv1 = bias[16 + nlo] * (lo8 ? 2.0f * LOG2E : -LOG2E);

    // ---- stage x halo tile (fp32 -> fp16) ----
    for (int l = tid; l < LH * LW; l += 256) {
        int r = l / LW, c = l - r * LW;
        int gy = by * THT + r - 1, gx = bx * TW + c - 1;
        half4 vh = {(_Float16)0, (_Float16)0, (_Float16)0, (_Float16)0};
        if ((unsigned)gy < HH && (unsigned)gx < WW) {
            const float* p = xg + (((size_t)(b * TT + t) * HH + gy) * WW + gx) * CIN;
            vh.x = (_Float16)p[0]; vh.y = (_Float16)p[1]; vh.z = (_Float16)p[2];
        }
        xls[l] = vh;
    }
    // ---- stage h halo tile ----
    if (MODE != 0) {
        for (int l = tid; l < LH * LW; l += 256) {
            int r = l / LW, c = l - r * LW;
            int gy = by * THT + r - 1, gx = bx * TW + c - 1;
            half8 v = {(_Float16)0, (_Float16)0, (_Float16)0, (_Float16)0,
                       (_Float16)0, (_Float16)0, (_Float16)0, (_Float16)0};
            if ((unsigned)gy < HH && (unsigned)gx < WW)
                v = *(const half8*)(hin + ((size_t)(b * HH + gy) * WW + gx) * FF);
            hls[l] = v;
        }
    }
    __syncthreads();

    // fused-epilogue constants (MODE 2)
    float bn_s = 0.f, bn_b = 0.f, dw0 = 0.f, dw1 = 0.f, db0 = 0.f, db1 = 0.f;
    if (MODE == 2) {
        bn_s = gamma[fc] * rsqrtf(var[fc] + 1e-3f);
        bn_b = beta[fc] - mean[fc] * bn_s;
        dw0 = dw[fc * 2 + 0]; dw1 = dw[fc * 2 + 1];
        db0 = db[0]; db1 = db[1];
    }

#pragma unroll
    for (int g = 0; g < NG; ++g) {
        const int lr  = wave * 4 + (g >> 1);   // local row of this strip
        const int gx0 = (g & 1) * 16;          // strip start col
        const int lc  = gx0 + nlo;             // A-op: m = lane&15 -> pixel col

        // ---- x A fragments from LDS ----
        const int t0 = 2 * quad, t1 = t0 + 1;
        half4 p = xls[(lr + t0 / 3) * LW + lc + t0 % 3];
        half4 q = xls[(lr + t1 / 3) * LW + lc + t1 % 3];
        half4 s = xls[(lr + 2) * LW + lc + 2];            // tap 8
        half8 a_xA = (half8){p.x, p.y, p.z, p.w, q.x, q.y, q.z, q.w};
        half8 a_xB = (half8){s.x, s.y, s.z, s.w, s.x, s.y, s.z, s.w};

        floatx4 acc0 = {bv0, bv0, bv0, bv0};
        floatx4 acc1 = {bv1, bv1, bv1, bv1};
        acc0 = MFMA(a_xA, bfh[0], acc0);  acc1 = MFMA(a_xA, bfh[1], acc1);
        acc0 = MFMA(a_xB, bfh[2], acc0);  acc1 = MFMA(a_xB, bfh[3], acc1);
        acc0 = MFMA(a_xA, bfl[0], acc0);  acc1 = MFMA(a_xA, bfl[1], acc1);
        acc0 = MFMA(a_xB, bfl[2], acc0);  acc1 = MFMA(a_xB, bfl[3], acc1);
        if (MODE != 0) {
#pragma unroll
            for (int c = 0; c < 3; ++c) {
                int tap = c * 4 + quad;
                if (tap > 8) tap = 8;          // padded taps: B rows zero
                half8 ah = hls[(lr + tap / 3) * LW + lc + tap % 3];
                acc0 = MFMA(ah, bfh[4 + c * 2], acc0);
                acc1 = MFMA(ah, bfh[5 + c * 2], acc1);
                acc0 = MFMA(ah, bfl[4 + c * 2], acc0);
                acc1 = MFMA(ah, bfl[5 + c * 2], acc1);
            }
        }

        // ---- gate phase ----
        // C layout: pixel m = quad*4+reg, ch = nlo (acc0) / nlo+16 (acc1).
        // Lanes ch<8 hold (i,g), ch+8 hold (f,o): exchange via shfl_xor(8).
        float s0 = lo8 ? acc0[2] : acc0[0]; float r0 = __shfl_xor(s0, 8, 64);
        float s1 = lo8 ? acc0[3] : acc0[1]; float r1 = __shfl_xor(s1, 8, 64);
        float s2 = lo8 ? acc1[2] : acc1[0]; float r2 = __shfl_xor(s2, 8, 64);
        float s3 = lo8 ? acc1[3] : acc1[1]; float r3 = __shfl_xor(s3, 8, 64);

        const float zi0 = lo8 ? acc0[0] : r0, zi1 = lo8 ? acc0[1] : r1;
        const float zf0 = lo8 ? r0 : acc0[2], zf1 = lo8 ? r1 : acc0[3];
        const float zg0 = lo8 ? acc1[0] : r2, zg1 = lo8 ? acc1[1] : r3;
        const float zo0 = lo8 ? r2 : acc1[2], zo1 = lo8 ? r3 : acc1[3];

        float c0 = 0.f, c1 = 0.f;
        if (MODE != 0) { c0 = (float)cpre[g].x; c1 = (float)cpre[g].y; }

        const float ii0 = sig2(zi0), ff0 = sig2(zf0), gg0 = tanh2(zg0), oo0 = sig2(zo0);
        const float cn0 = ff0 * c0 + ii0 * gg0;
        const float hn0 = oo0 * tanh2(cn0 * (2.0f * LOG2E));
        const float ii1 = sig2(zi1), ff1 = sig2(zf1), gg1 = tanh2(zg1), oo1 = sig2(zo1);
        const float cn1 = ff1 * c1 + ii1 * gg1;
        const float hn1 = oo1 * tanh2(cn1 * (2.0f * LOG2E));

        const int m0 = quad * 4 + (lo8 ? 0 : 2);
        const int gy = by * THT + lr;
        if (MODE != 2) {
            // c writeback (fp16 packed, coalesced dword per lane)
            half2t cc; cc.x = (_Float16)cn0; cc.y = (_Float16)cn1;
            ((half2t*)cbuf)[(size_t)(gidbase + g) * 64 + lane] = cc;
            // h writeback: lane owns channel fc for pixels m0, m0+1
            _Float16* hp = hout + ((size_t)(b * HH + gy) * WW + bx * TW + gx0 + m0) * FF + fc;
            hp[0]  = (_Float16)hn0;
            hp[FF] = (_Float16)hn1;
        } else {
            // ---- fused epilogue: BN -> LeakyReLU(0.3) -> Dense(8->2) ----
            float y0 = bn_s * hn0 + bn_b; y0 = (y0 >= 0.f) ? y0 : 0.3f * y0;
            float y1 = bn_s * hn1 + bn_b; y1 = (y1 >= 0.f) ? y1 : 0.3f * y1;
            float p00 = y0 * dw0, p01 = y0 * dw1;
            float p10 = y1 * dw0, p11 = y1 * dw1;
#pragma unroll
            for (int m = 1; m <= 4; m <<= 1) {
                p00 += __shfl_xor(p00, m, 64);
                p01 += __shfl_xor(p01, m, 64);
                p10 += __shfl_xor(p10, m, 64);
                p11 += __shfl_xor(p11, m, 64);
            }
            const int j = nlo & 7;
            if (j < 4) {
                const int px = m0 + (j >> 1);
                const int k  = j & 1;
                float val = (j == 0 ? p00 : j == 1 ? p01 : j == 2 ? p10 : p11)
                            + (k ? db1 : db0);
                out[((size_t)(b * HH + gy) * WW + bx * TW + gx0 + px) * 2 + k] = val;
            }
        }
    }
}

extern "C" void kernel_launch(void* const* d_in, const int* in_sizes, int n_in,
                              void* d_out, int out_size, void* d_ws, size_t ws_size,
                              hipStream_t stream) {
    const float* x     = (const float*)d_in[0];
    const float* wk    = (const float*)d_in[1];
    const float* wr    = (const float*)d_in[2];
    const float* bias  = (const float*)d_in[3];
    const float* gamma = (const float*)d_in[4];
    const float* beta  = (const float*)d_in[5];
    const float* mean  = (const float*)d_in[6];
    const float* var   = (const float*)d_in[7];
    const float* dw    = (const float*)d_in[8];
    const float* db    = (const float*)d_in[9];
    float* out = (float*)d_out;

    // ws: blob 32KB | cbuf fp16 16.78MB | h0 fp16 16.78MB | h1 fp16 16.78MB
    const size_t state = (size_t)BB * HH * WW * FF;
    _Float16* blob = (_Float16*)d_ws;
    _Float16* cbuf = (_Float16*)((char*)d_ws + 32768);
    _Float16* h0   = (_Float16*)((char*)cbuf + state * 2);
    _Float16* h1   = (_Float16*)((char*)h0 + state * 2);

    build_frags<<<1, 64, 0, stream>>>(wk, wr, blob);

    dim3 grid(WW / TW, HH / THT, BB);   // (8,16,16) = 2048 blocks
    dim3 block(256);
    _Float16* bufs[2] = {h0, h1};
    // step t reads bufs[t&1], writes bufs[(t+1)&1]
    lstm_step<0><<<grid, block, 0, stream>>>(x, 0, blob, bias, h0, bufs[1], cbuf,
                                             gamma, beta, mean, var, dw, db, out);
    for (int t = 1; t < TT - 1; ++t)
        lstm_step<1><<<grid, block, 0, stream>>>(x, t, blob, bias, bufs[t & 1],
                                                 bufs[(t + 1) & 1], cbuf,
                                                 gamma, beta, mean, var, dw, db, out);
    lstm_step<2><<<grid, block, 0, stream>>>(x, TT - 1, blob, bias, bufs[(TT - 1) & 1],
                                             nullptr, cbuf,
                                             gamma, beta, mean, var, dw, db, out);
}

// Round 8
// 263.341 us; speedup vs baseline: 3.7584x; 1.0146x over previous
//
#include <hip/hip_runtime.h>

// ConvLSTM2D (B=16,T=5,H=W=256,Cin=3,F=8) + BN + LeakyReLU + Dense(8->2)
// Multi-launch, one kernel per timestep, h fp16 ping-pong, c fp16 custom
// layout, epilogue fused into t=4, exp2-folded weights. Round-8 deltas:
//  - __launch_bounds__(256,2): allow ~256 VGPR so all 16 B-fragments stay
//    RESIDENT (round 7: VGPR=76 < 80 needed -> compiler reloaded frags from
//    L1 inside the group loop = the latency bubbles behind VALUBusy 40%).
//  - x-lo MFMAs actually removed (16 MFMA/group, 16 frags = 64 VGPR).

#define BB  16
#define TT  5
#define HH  256
#define WW  256
#define CIN 3
#define FF  8
#define GG  32

#define TW  32   // tile width (pixels)
#define THT 16   // tile height
#define LW  34   // TW+2 halo
#define LH  18   // THT+2 halo
#define NG  8    // 16x16-px groups per wave

#define LOG2E 1.44269504088896340736f

typedef _Float16 half8  __attribute__((ext_vector_type(8)));
typedef _Float16 half4  __attribute__((ext_vector_type(4)));
typedef _Float16 half2t __attribute__((ext_vector_type(2)));
typedef float    floatx4 __attribute__((ext_vector_type(4)));

__device__ __forceinline__ float frcp(float x) { return __builtin_amdgcn_rcpf(x); }
// z pre-scaled by -log2e:  sigmoid(z0) = 1/(1+2^z)
__device__ __forceinline__ float sig2(float z)  { return frcp(1.0f + __builtin_amdgcn_exp2f(z)); }
// z pre-scaled by +2log2e: tanh(z0) = 1 - 2/(1+2^z)
__device__ __forceinline__ float tanh2(float z) { return 1.0f - 2.0f * frcp(1.0f + __builtin_amdgcn_exp2f(z)); }

#define MFMA(A, B, C) __builtin_amdgcn_mfma_f32_16x16x32_f16((A), (B), (C), 0, 0, 0)

// ---------------------------------------------------------------------------
// Setup: 16 B-fragments, activation scale folded per column:
// cols 0..15 (i,f) and 24..31 (o): *(-log2e); cols 16..23 (g): *(+2log2e).
// Layout: frag 0..9 = hi (chunks 0..4 x 2 col-halves); frag 10..15 = lo for
// h-conv chunks 2..4 only (x-conv lo dropped: error ~2.6e-4/step).
// MFMA B layout: n = lane&15, k = quad*8+j.
// K-chunks: 0: x taps0-7 (k=tap*4+ci, ci padded to 4)
//           1: x tap8   (k=ci, only k<3 nonzero)
//           2..4: h taps [4c..4c+3] (k=(tap-4c)*8+ci), taps>8 zero
// ---------------------------------------------------------------------------
__global__ void build_frags(const float* __restrict__ wk,
                            const float* __restrict__ wr,
                            _Float16* __restrict__ blob) {
    const int lane = threadIdx.x & 63;
    const int quad = lane >> 4, nlo = lane & 15;
    for (int chunk = 0; chunk < 5; ++chunk) {
        for (int nh = 0; nh < 2; ++nh) {
            const int n = nh * 16 + nlo;
            const float scale = (n >= 16 && n < 24) ? (2.0f * LOG2E) : (-LOG2E);
            const int frag = chunk * 2 + nh;
            _Float16* dhi = blob + ((size_t)frag * 64 + lane) * 8;
            _Float16* dlo = (chunk >= 2)
                ? blob + ((size_t)(10 + (chunk - 2) * 2 + nh) * 64 + lane) * 8
                : nullptr;
            for (int j = 0; j < 8; ++j) {
                const int k = quad * 8 + j;
                float w = 0.0f;
                if (chunk == 0) {
                    int tap = k >> 2, ci = k & 3;
                    if (ci < 3) w = wk[(tap * 3 + ci) * GG + n];
                } else if (chunk == 1) {
                    if (quad == 0 && j < 3) w = wk[(8 * 3 + j) * GG + n];
                } else {
                    int c = chunk - 2;
                    int tap = c * 4 + quad, ci = j;
                    if (tap < 9) w = wr[(tap * FF + ci) * GG + n];
                }
                w *= scale;
                _Float16 wh = (_Float16)w;
                dhi[j] = wh;
                if (dlo) dlo[j] = (_Float16)(w - (float)wh);
            }
        }
    }
}

// ---------------------------------------------------------------------------
// One ConvLSTM timestep. MODE: 0=first (no h/c in), 1=mid, 2=last (+epilogue).
// Block = 256 thr (4 waves), tile 32x16 px; grid (8,16,16) = 2048 blocks.
// __launch_bounds__(256,2): 2 blocks/CU target -> VGPR budget ~256, frags
// stay resident (round-7 default budget of 76 forced per-group reloads).
// ---------------------------------------------------------------------------
template <int MODE>
__global__ __launch_bounds__(256, 2) void lstm_step(
    const float* __restrict__ xg,       // [B,T,H,W,3] fp32
    int t,
    const _Float16* __restrict__ blob,  // scaled B-fragments (hi 0..9, lo 10..15)
    const float* __restrict__ bias,     // [32] (unscaled; scaled here)
    const _Float16* __restrict__ hin,   // h(t-1) fp16
    _Float16* __restrict__ hout,        // h(t) fp16
    _Float16* __restrict__ cbuf,        // c fp16, [group][lane]{2} custom layout
    const float* __restrict__ gamma, const float* __restrict__ beta,
    const float* __restrict__ mean,  const float* __restrict__ var,
    const float* __restrict__ dw,    const float* __restrict__ db,
    float* __restrict__ out)            // [B,H,W,2] (MODE 2 only)
{
    __shared__ half8 hls[LH * LW];     // h tile + halo
    __shared__ half4 xls[LH * LW];     // x tile + halo (3ch + pad)

    const int tid  = threadIdx.x;
    const int bx = blockIdx.x, by = blockIdx.y, b = blockIdx.z;
    const int lane = tid & 63, wave = tid >> 6;
    const int quad = lane >> 4, nlo = lane & 15;
    const bool lo8 = (nlo < 8);
    const int fc = nlo & 7;

    const int gidbase = (((b * (int)gridDim.y + by) * (int)gridDim.x + bx) * 4 + wave) * NG;

    // ---- prefetch c for all groups (in flight during LDS staging) ----
    half2t cpre[NG];
    if (MODE != 0) {
#pragma unroll
        for (int g = 0; g < NG; ++g)
            cpre[g] = ((const half2t*)cbuf)[(size_t)(gidbase + g) * 64 + lane];
    }

    // B-fragments -> registers, resident for the whole kernel
    half8 bfh[10], bfl[6];
#pragma unroll
    for (int i = 0; i < 10; ++i)
        bfh[i] = *(const half8*)(blob + ((size_t)i * 64 + lane) * 8);
#pragma unroll
    for (int i = 0; i < 6; ++i)
        bfl[i] = *(const half8*)(blob + ((size_t)(10 + i) * 64 + lane) * 8);

    // bias, activation-scale folded (cols 16..23 are the g gate)
    const float bv0 = bias[nlo] * (-LOG2E);
    const float bv1 = bias[16 + nlo] * (lo8 ? 2.0f * LOG2E : -LOG2E);

    // ---- stage x halo tile (fp32 -> fp16) ----
    for (int l = tid; l < LH * LW; l += 256) {
        int r = l / LW, c = l - r * LW;
        int gy = by * THT + r - 1, gx = bx * TW + c - 1;
        half4 vh = {(_Float16)0, (_Float16)0, (_Float16)0, (_Float16)0};
        if ((unsigned)gy < HH && (unsigned)gx < WW) {
            const float* p = xg + (((size_t)(b * TT + t) * HH + gy) * WW + gx) * CIN;
            vh.x = (_Float16)p[0]; vh.y = (_Float16)p[1]; vh.z = (_Float16)p[2];
        }
        xls[l] = vh;
    }
    // ---- stage h halo tile ----
    if (MODE != 0) {
        for (int l = tid; l < LH * LW; l += 256) {
            int r = l / LW, c = l - r * LW;
            int gy = by * THT + r - 1, gx = bx * TW + c - 1;
            half8 v = {(_Float16)0, (_Float16)0, (_Float16)0, (_Float16)0,
                       (_Float16)0, (_Float16)0, (_Float16)0, (_Float16)0};
            if ((unsigned)gy < HH && (unsigned)gx < WW)
                v = *(const half8*)(hin + ((size_t)(b * HH + gy) * WW + gx) * FF);
            hls[l] = v;
        }
    }
    __syncthreads();

    // fused-epilogue constants (MODE 2)
    float bn_s = 0.f, bn_b = 0.f, dw0 = 0.f, dw1 = 0.f, db0 = 0.f, db1 = 0.f;
    if (MODE == 2) {
        bn_s = gamma[fc] * rsqrtf(var[fc] + 1e-3f);
        bn_b = beta[fc] - mean[fc] * bn_s;
        dw0 = dw[fc * 2 + 0]; dw1 = dw[fc * 2 + 1];
        db0 = db[0]; db1 = db[1];
    }

#pragma unroll
    for (int g = 0; g < NG; ++g) {
        const int lr  = wave * 4 + (g >> 1);   // local row of this strip
        const int gx0 = (g & 1) * 16;          // strip start col
        const int lc  = gx0 + nlo;             // A-op: m = lane&15 -> pixel col

        // ---- x A fragments from LDS ----
        const int t0 = 2 * quad, t1 = t0 + 1;
        half4 p = xls[(lr + t0 / 3) * LW + lc + t0 % 3];
        half4 q = xls[(lr + t1 / 3) * LW + lc + t1 % 3];
        half4 s = xls[(lr + 2) * LW + lc + 2];            // tap 8
        half8 a_xA = (half8){p.x, p.y, p.z, p.w, q.x, q.y, q.z, q.w};
        half8 a_xB = (half8){s.x, s.y, s.z, s.w, s.x, s.y, s.z, s.w};

        floatx4 acc0 = {bv0, bv0, bv0, bv0};
        floatx4 acc1 = {bv1, bv1, bv1, bv1};
        acc0 = MFMA(a_xA, bfh[0], acc0);  acc1 = MFMA(a_xA, bfh[1], acc1);
        acc0 = MFMA(a_xB, bfh[2], acc0);  acc1 = MFMA(a_xB, bfh[3], acc1);
        if (MODE != 0) {
#pragma unroll
            for (int c = 0; c < 3; ++c) {
                int tap = c * 4 + quad;
                if (tap > 8) tap = 8;          // padded taps: B rows zero
                half8 ah = hls[(lr + tap / 3) * LW + lc + tap % 3];
                acc0 = MFMA(ah, bfh[4 + c * 2], acc0);
                acc1 = MFMA(ah, bfh[5 + c * 2], acc1);
                acc0 = MFMA(ah, bfl[c * 2 + 0], acc0);
                acc1 = MFMA(ah, bfl[c * 2 + 1], acc1);
            }
        }

        // ---- gate phase ----
        // C layout: pixel m = quad*4+reg, ch = nlo (acc0) / nlo+16 (acc1).
        // Lanes ch<8 hold (i,g), ch+8 hold (f,o): exchange via shfl_xor(8).
        float s0 = lo8 ? acc0[2] : acc0[0]; float r0 = __shfl_xor(s0, 8, 64);
        float s1 = lo8 ? acc0[3] : acc0[1]; float r1 = __shfl_xor(s1, 8, 64);
        float s2 = lo8 ? acc1[2] : acc1[0]; float r2 = __shfl_xor(s2, 8, 64);
        float s3 = lo8 ? acc1[3] : acc1[1]; float r3 = __shfl_xor(s3, 8, 64);

        const float zi0 = lo8 ? acc0[0] : r0, zi1 = lo8 ? acc0[1] : r1;
        const float zf0 = lo8 ? r0 : acc0[2], zf1 = lo8 ? r1 : acc0[3];
        const float zg0 = lo8 ? acc1[0] : r2, zg1 = lo8 ? acc1[1] : r3;
        const float zo0 = lo8 ? r2 : acc1[2], zo1 = lo8 ? r3 : acc1[3];

        float c0 = 0.f, c1 = 0.f;
        if (MODE != 0) { c0 = (float)cpre[g].x; c1 = (float)cpre[g].y; }

        const float ii0 = sig2(zi0), ff0 = sig2(zf0), gg0 = tanh2(zg0), oo0 = sig2(zo0);
        const float cn0 = ff0 * c0 + ii0 * gg0;
        const float hn0 = oo0 * tanh2(cn0 * (2.0f * LOG2E));
        const float ii1 = sig2(zi1), ff1 = sig2(zf1), gg1 = tanh2(zg1), oo1 = sig2(zo1);
        const float cn1 = ff1 * c1 + ii1 * gg1;
        const float hn1 = oo1 * tanh2(cn1 * (2.0f * LOG2E));

        const int m0 = quad * 4 + (lo8 ? 0 : 2);
        const int gy = by * THT + lr;
        if (MODE != 2) {
            // c writeback (fp16 packed, coalesced dword per lane)
            half2t cc; cc.x = (_Float16)cn0; cc.y = (_Float16)cn1;
            ((half2t*)cbuf)[(size_t)(gidbase + g) * 64 + lane] = cc;
            // h writeback: lane owns channel fc for pixels m0, m0+1
            _Float16* hp = hout + ((size_t)(b * HH + gy) * WW + bx * TW + gx0 + m0) * FF + fc;
            hp[0]  = (_Float16)hn0;
            hp[FF] = (_Float16)hn1;
        } else {
            // ---- fused epilogue: BN -> LeakyReLU(0.3) -> Dense(8->2) ----
            float y0 = bn_s * hn0 + bn_b; y0 = (y0 >= 0.f) ? y0 : 0.3f * y0;
            float y1 = bn_s * hn1 + bn_b; y1 = (y1 >= 0.f) ? y1 : 0.3f * y1;
            float p00 = y0 * dw0, p01 = y0 * dw1;
            float p10 = y1 * dw0, p11 = y1 * dw1;
#pragma unroll
            for (int m = 1; m <= 4; m <<= 1) {
                p00 += __shfl_xor(p00, m, 64);
                p01 += __shfl_xor(p01, m, 64);
                p10 += __shfl_xor(p10, m, 64);
                p11 += __shfl_xor(p11, m, 64);
            }
            const int j = nlo & 7;
            if (j < 4) {
                const int px = m0 + (j >> 1);
                const int k  = j & 1;
                float val = (j == 0 ? p00 : j == 1 ? p01 : j == 2 ? p10 : p11)
                            + (k ? db1 : db0);
                out[((size_t)(b * HH + gy) * WW + bx * TW + gx0 + px) * 2 + k] = val;
            }
        }
    }
}

extern "C" void kernel_launch(void* const* d_in, const int* in_sizes, int n_in,
                              void* d_out, int out_size, void* d_ws, size_t ws_size,
                              hipStream_t stream) {
    const float* x     = (const float*)d_in[0];
    const float* wk    = (const float*)d_in[1];
    const float* wr    = (const float*)d_in[2];
    const float* bias  = (const float*)d_in[3];
    const float* gamma = (const float*)d_in[4];
    const float* beta  = (const float*)d_in[5];
    const float* mean  = (const float*)d_in[6];
    const float* var   = (const float*)d_in[7];
    const float* dw    = (const float*)d_in[8];
    const float* db    = (const float*)d_in[9];
    float* out = (float*)d_out;

    // ws: blob 32KB | cbuf fp16 16.78MB | h0 fp16 16.78MB | h1 fp16 16.78MB
    const size_t state = (size_t)BB * HH * WW * FF;
    _Float16* blob = (_Float16*)d_ws;
    _Float16* cbuf = (_Float16*)((char*)d_ws + 32768);
    _Float16* h0   = (_Float16*)((char*)cbuf + state * 2);
    _Float16* h1   = (_Float16*)((char*)h0 + state * 2);

    build_frags<<<1, 64, 0, stream>>>(wk, wr, blob);

    dim3 grid(WW / TW, HH / THT, BB);   // (8,16,16) = 2048 blocks
    dim3 block(256);
    _Float16* bufs[2] = {h0, h1};
    // step t reads bufs[t&1], writes bufs[(t+1)&1]
    lstm_step<0><<<grid, block, 0, stream>>>(x, 0, blob, bias, h0, bufs[1], cbuf,
                                             gamma, beta, mean, var, dw, db, out);
    for (int t = 1; t < TT - 1; ++t)
        lstm_step<1><<<grid, block, 0, stream>>>(x, t, blob, bias, bufs[t & 1],
                                                 bufs[(t + 1) & 1], cbuf,
                                                 gamma, beta, mean, var, dw, db, out);
    lstm_step<2><<<grid, block, 0, stream>>>(x, TT - 1, blob, bias, bufs[(TT - 1) & 1],
                                             nullptr, cbuf,
                                             gamma, beta, mean, var, dw, db, out);
}

// Round 9
// 255.355 us; speedup vs baseline: 3.8759x; 1.0313x over previous
//
#include <hip/hip_runtime.h>

// ConvLSTM2D (B=16,T=5,H=W=256,Cin=3,F=8) + BN + LeakyReLU + Dense(8->2)
// Multi-launch, one kernel per timestep, h fp16 ping-pong, c fp16 custom
// layout, epilogue fused into t=4, exp2-folded weights.
// Round-9 delta: TWO-PHASE STAGING for MLP. r4/r7/r8 all plateau at ~43us/step
// with hbm ~1.5 TB/s, occupancy 17%, nothing saturated -> latency-bound with
// ~2KB in flight per CU (staging loop serialized: load->wait->ds_write x3).
// Now: all global loads (c, frags, 9 x-dwords, 3 h-16B per thread) issued
// back-to-back into registers, THEN all cvt+ds_write. ~10KB/wave in flight.

#define BB  16
#define TT  5
#define HH  256
#define WW  256
#define CIN 3
#define FF  8
#define GG  32

#define TW  32   // tile width (pixels)
#define THT 16   // tile height
#define LW  34   // TW+2 halo
#define LH  18   // THT+2 halo
#define NG  8    // 16x16-px groups per wave

#define LOG2E 1.44269504088896340736f

typedef _Float16 half8  __attribute__((ext_vector_type(8)));
typedef _Float16 half4  __attribute__((ext_vector_type(4)));
typedef _Float16 half2t __attribute__((ext_vector_type(2)));
typedef float    floatx4 __attribute__((ext_vector_type(4)));

__device__ __forceinline__ float frcp(float x) { return __builtin_amdgcn_rcpf(x); }
// z pre-scaled by -log2e:  sigmoid(z0) = 1/(1+2^z)
__device__ __forceinline__ float sig2(float z)  { return frcp(1.0f + __builtin_amdgcn_exp2f(z)); }
// z pre-scaled by +2log2e: tanh(z0) = 1 - 2/(1+2^z)
__device__ __forceinline__ float tanh2(float z) { return 1.0f - 2.0f * frcp(1.0f + __builtin_amdgcn_exp2f(z)); }

#define MFMA(A, B, C) __builtin_amdgcn_mfma_f32_16x16x32_f16((A), (B), (C), 0, 0, 0)

// ---------------------------------------------------------------------------
// Setup: 16 B-fragments, activation scale folded per column:
// cols 0..15 (i,f) and 24..31 (o): *(-log2e); cols 16..23 (g): *(+2log2e).
// frag 0..9 = hi (chunks 0..4 x 2 col-halves); frag 10..15 = lo for h-conv
// chunks 2..4 (x-conv lo dropped). MFMA B layout: n = lane&15, k = quad*8+j.
// K-chunks: 0: x taps0-7 (k=tap*4+ci, ci padded to 4)
//           1: x tap8   (k=ci, only k<3 nonzero)
//           2..4: h taps [4c..4c+3] (k=(tap-4c)*8+ci), taps>8 zero
// ---------------------------------------------------------------------------
__global__ void build_frags(const float* __restrict__ wk,
                            const float* __restrict__ wr,
                            _Float16* __restrict__ blob) {
    const int lane = threadIdx.x & 63;
    const int quad = lane >> 4, nlo = lane & 15;
    for (int chunk = 0; chunk < 5; ++chunk) {
        for (int nh = 0; nh < 2; ++nh) {
            const int n = nh * 16 + nlo;
            const float scale = (n >= 16 && n < 24) ? (2.0f * LOG2E) : (-LOG2E);
            const int frag = chunk * 2 + nh;
            _Float16* dhi = blob + ((size_t)frag * 64 + lane) * 8;
            _Float16* dlo = (chunk >= 2)
                ? blob + ((size_t)(10 + (chunk - 2) * 2 + nh) * 64 + lane) * 8
                : nullptr;
            for (int j = 0; j < 8; ++j) {
                const int k = quad * 8 + j;
                float w = 0.0f;
                if (chunk == 0) {
                    int tap = k >> 2, ci = k & 3;
                    if (ci < 3) w = wk[(tap * 3 + ci) * GG + n];
                } else if (chunk == 1) {
                    if (quad == 0 && j < 3) w = wk[(8 * 3 + j) * GG + n];
                } else {
                    int c = chunk - 2;
                    int tap = c * 4 + quad, ci = j;
                    if (tap < 9) w = wr[(tap * FF + ci) * GG + n];
                }
                w *= scale;
                _Float16 wh = (_Float16)w;
                dhi[j] = wh;
                if (dlo) dlo[j] = (_Float16)(w - (float)wh);
            }
        }
    }
}

// ---------------------------------------------------------------------------
// One ConvLSTM timestep. MODE: 0=first (no h/c in), 1=mid, 2=last (+epilogue).
// Block = 256 thr (4 waves), tile 32x16 px; grid (8,16,16) = 2048 blocks.
// ---------------------------------------------------------------------------
template <int MODE>
__global__ __launch_bounds__(256) void lstm_step(
    const float* __restrict__ xg,       // [B,T,H,W,3] fp32
    int t,
    const _Float16* __restrict__ blob,  // scaled B-fragments (hi 0..9, lo 10..15)
    const float* __restrict__ bias,     // [32] (unscaled; scaled here)
    const _Float16* __restrict__ hin,   // h(t-1) fp16
    _Float16* __restrict__ hout,        // h(t) fp16
    _Float16* __restrict__ cbuf,        // c fp16, [group][lane]{2} custom layout
    const float* __restrict__ gamma, const float* __restrict__ beta,
    const float* __restrict__ mean,  const float* __restrict__ var,
    const float* __restrict__ dw,    const float* __restrict__ db,
    float* __restrict__ out)            // [B,H,W,2] (MODE 2 only)
{
    __shared__ half8 hls[LH * LW];     // h tile + halo
    __shared__ half4 xls[LH * LW];     // x tile + halo (3ch + pad)

    const int tid  = threadIdx.x;
    const int bx = blockIdx.x, by = blockIdx.y, b = blockIdx.z;
    const int lane = tid & 63, wave = tid >> 6;
    const int quad = lane >> 4, nlo = lane & 15;
    const bool lo8 = (nlo < 8);
    const int fc = nlo & 7;

    const int gidbase = (((b * (int)gridDim.y + by) * (int)gridDim.x + bx) * 4 + wave) * NG;

    // ================= PHASE A: issue ALL global loads =================
    // c prefetch (8 x dword)
    half2t cpre[NG];
    if (MODE != 0) {
#pragma unroll
        for (int g = 0; g < NG; ++g)
            cpre[g] = ((const half2t*)cbuf)[(size_t)(gidbase + g) * 64 + lane];
    }
    // B-fragments (16 x 16B, L2-hot)
    half8 bfh[10], bfl[6];
#pragma unroll
    for (int i = 0; i < 10; ++i)
        bfh[i] = *(const half8*)(blob + ((size_t)i * 64 + lane) * 8);
#pragma unroll
    for (int i = 0; i < 6; ++i)
        bfl[i] = *(const half8*)(blob + ((size_t)(10 + i) * 64 + lane) * 8);

    // x halo: 612 px, 3 slots/thread, 3 dwords each -> 9 loads in flight
    float xr[3][3];
    bool  xin[3];
#pragma unroll
    for (int k = 0; k < 3; ++k) {
        const int l = tid + k * 256;
        const bool in = (l < LH * LW);
        xin[k] = in;
        int r = l / LW, c = l - r * LW;
        int gy = by * THT + r - 1, gx = bx * TW + c - 1;
        const bool inb = in && (unsigned)gy < HH && (unsigned)gx < WW;
        const float* p = xg + (((size_t)(b * TT + t) * HH + gy) * WW + gx) * CIN;
        xr[k][0] = inb ? p[0] : 0.0f;
        xr[k][1] = inb ? p[1] : 0.0f;
        xr[k][2] = inb ? p[2] : 0.0f;
    }
    // h halo: 612 px, 3 slots/thread, 16B each -> 3 loads in flight
    half8 hr[3];
    if (MODE != 0) {
#pragma unroll
        for (int k = 0; k < 3; ++k) {
            const int l = tid + k * 256;
            const bool in = (l < LH * LW);
            int r = l / LW, c = l - r * LW;
            int gy = by * THT + r - 1, gx = bx * TW + c - 1;
            const bool inb = in && (unsigned)gy < HH && (unsigned)gx < WW;
            half8 v = {(_Float16)0, (_Float16)0, (_Float16)0, (_Float16)0,
                       (_Float16)0, (_Float16)0, (_Float16)0, (_Float16)0};
            if (inb) v = *(const half8*)(hin + ((size_t)(b * HH + gy) * WW + gx) * FF);
            hr[k] = v;
        }
    }

    // ================= PHASE B: LDS writes =================
#pragma unroll
    for (int k = 0; k < 3; ++k) {
        if (xin[k]) {
            half4 vh;
            vh.x = (_Float16)xr[k][0];
            vh.y = (_Float16)xr[k][1];
            vh.z = (_Float16)xr[k][2];
            vh.w = (_Float16)0;
            xls[tid + k * 256] = vh;
        }
    }
    if (MODE != 0) {
#pragma unroll
        for (int k = 0; k < 3; ++k)
            if (xin[k]) hls[tid + k * 256] = hr[k];
    }
    __syncthreads();

    // bias, activation-scale folded (cols 16..23 are the g gate)
    const float bv0 = bias[nlo] * (-LOG2E);
    const float bv1 = bias[16 + nlo] * (lo8 ? 2.0f * LOG2E : -LOG2E);

    // fused-epilogue constants (MODE 2)
    float bn_s = 0.f, bn_b = 0.f, dw0 = 0.f, dw1 = 0.f, db0 = 0.f, db1 = 0.f;
    if (MODE == 2) {
        bn_s = gamma[fc] * rsqrtf(var[fc] + 1e-3f);
        bn_b = beta[fc] - mean[fc] * bn_s;
        dw0 = dw[fc * 2 + 0]; dw1 = dw[fc * 2 + 1];
        db0 = db[0]; db1 = db[1];
    }

#pragma unroll
    for (int g = 0; g < NG; ++g) {
        const int lr  = wave * 4 + (g >> 1);   // local row of this strip
        const int gx0 = (g & 1) * 16;          // strip start col
        const int lc  = gx0 + nlo;             // A-op: m = lane&15 -> pixel col

        // ---- x A fragments from LDS ----
        const int t0 = 2 * quad, t1 = t0 + 1;
        half4 p = xls[(lr + t0 / 3) * LW + lc + t0 % 3];
        half4 q = xls[(lr + t1 / 3) * LW + lc + t1 % 3];
        half4 s = xls[(lr + 2) * LW + lc + 2];            // tap 8
        half8 a_xA = (half8){p.x, p.y, p.z, p.w, q.x, q.y, q.z, q.w};
        half8 a_xB = (half8){s.x, s.y, s.z, s.w, s.x, s.y, s.z, s.w};

        floatx4 acc0 = {bv0, bv0, bv0, bv0};
        floatx4 acc1 = {bv1, bv1, bv1, bv1};
        acc0 = MFMA(a_xA, bfh[0], acc0);  acc1 = MFMA(a_xA, bfh[1], acc1);
        acc0 = MFMA(a_xB, bfh[2], acc0);  acc1 = MFMA(a_xB, bfh[3], acc1);
        if (MODE != 0) {
#pragma unroll
            for (int c = 0; c < 3; ++c) {
                int tap = c * 4 + quad;
                if (tap > 8) tap = 8;          // padded taps: B rows zero
                half8 ah = hls[(lr + tap / 3) * LW + lc + tap % 3];
                acc0 = MFMA(ah, bfh[4 + c * 2], acc0);
                acc1 = MFMA(ah, bfh[5 + c * 2], acc1);
                acc0 = MFMA(ah, bfl[c * 2 + 0], acc0);
                acc1 = MFMA(ah, bfl[c * 2 + 1], acc1);
            }
        }

        // ---- gate phase ----
        // C layout: pixel m = quad*4+reg, ch = nlo (acc0) / nlo+16 (acc1).
        // Lanes ch<8 hold (i,g), ch+8 hold (f,o): exchange via shfl_xor(8).
        float s0 = lo8 ? acc0[2] : acc0[0]; float r0 = __shfl_xor(s0, 8, 64);
        float s1 = lo8 ? acc0[3] : acc0[1]; float r1 = __shfl_xor(s1, 8, 64);
        float s2 = lo8 ? acc1[2] : acc1[0]; float r2 = __shfl_xor(s2, 8, 64);
        float s3 = lo8 ? acc1[3] : acc1[1]; float r3 = __shfl_xor(s3, 8, 64);

        const float zi0 = lo8 ? acc0[0] : r0, zi1 = lo8 ? acc0[1] : r1;
        const float zf0 = lo8 ? r0 : acc0[2], zf1 = lo8 ? r1 : acc0[3];
        const float zg0 = lo8 ? acc1[0] : r2, zg1 = lo8 ? acc1[1] : r3;
        const float zo0 = lo8 ? r2 : acc1[2], zo1 = lo8 ? r3 : acc1[3];

        float c0 = 0.f, c1 = 0.f;
        if (MODE != 0) { c0 = (float)cpre[g].x; c1 = (float)cpre[g].y; }

        const float ii0 = sig2(zi0), ff0 = sig2(zf0), gg0 = tanh2(zg0), oo0 = sig2(zo0);
        const float cn0 = ff0 * c0 + ii0 * gg0;
        const float hn0 = oo0 * tanh2(cn0 * (2.0f * LOG2E));
        const float ii1 = sig2(zi1), ff1 = sig2(zf1), gg1 = tanh2(zg1), oo1 = sig2(zo1);
        const float cn1 = ff1 * c1 + ii1 * gg1;
        const float hn1 = oo1 * tanh2(cn1 * (2.0f * LOG2E));

        const int m0 = quad * 4 + (lo8 ? 0 : 2);
        const int gy = by * THT + lr;
        if (MODE != 2) {
            // c writeback (fp16 packed, coalesced dword per lane)
            half2t cc; cc.x = (_Float16)cn0; cc.y = (_Float16)cn1;
            ((half2t*)cbuf)[(size_t)(gidbase + g) * 64 + lane] = cc;
            // h writeback: lane owns channel fc for pixels m0, m0+1
            _Float16* hp = hout + ((size_t)(b * HH + gy) * WW + bx * TW + gx0 + m0) * FF + fc;
            hp[0]  = (_Float16)hn0;
            hp[FF] = (_Float16)hn1;
        } else {
            // ---- fused epilogue: BN -> LeakyReLU(0.3) -> Dense(8->2) ----
            float y0 = bn_s * hn0 + bn_b; y0 = (y0 >= 0.f) ? y0 : 0.3f * y0;
            float y1 = bn_s * hn1 + bn_b; y1 = (y1 >= 0.f) ? y1 : 0.3f * y1;
            float p00 = y0 * dw0, p01 = y0 * dw1;
            float p10 = y1 * dw0, p11 = y1 * dw1;
#pragma unroll
            for (int m = 1; m <= 4; m <<= 1) {
                p00 += __shfl_xor(p00, m, 64);
                p01 += __shfl_xor(p01, m, 64);
                p10 += __shfl_xor(p10, m, 64);
                p11 += __shfl_xor(p11, m, 64);
            }
            const int j = nlo & 7;
            if (j < 4) {
                const int px = m0 + (j >> 1);
                const int k  = j & 1;
                float val = (j == 0 ? p00 : j == 1 ? p01 : j == 2 ? p10 : p11)
                            + (k ? db1 : db0);
                out[((size_t)(b * HH + gy) * WW + bx * TW + gx0 + px) * 2 + k] = val;
            }
        }
    }
}

extern "C" void kernel_launch(void* const* d_in, const int* in_sizes, int n_in,
                              void* d_out, int out_size, void* d_ws, size_t ws_size,
                              hipStream_t stream) {
    const float* x     = (const float*)d_in[0];
    const float* wk    = (const float*)d_in[1];
    const float* wr    = (const float*)d_in[2];
    const float* bias  = (const float*)d_in[3];
    const float* gamma = (const float*)d_in[4];
    const float* beta  = (const float*)d_in[5];
    const float* mean  = (const float*)d_in[6];
    const float* var   = (const float*)d_in[7];
    const float* dw    = (const float*)d_in[8];
    const float* db    = (const float*)d_in[9];
    float* out = (float*)d_out;

    // ws: blob 32KB | cbuf fp16 16.78MB | h0 fp16 16.78MB | h1 fp16 16.78MB
    const size_t state = (size_t)BB * HH * WW * FF;
    _Float16* blob = (_Float16*)d_ws;
    _Float16* cbuf = (_Float16*)((char*)d_ws + 32768);
    _Float16* h0   = (_Float16*)((char*)cbuf + state * 2);
    _Float16* h1   = (_Float16*)((char*)h0 + state * 2);

    build_frags<<<1, 64, 0, stream>>>(wk, wr, blob);

    dim3 grid(WW / TW, HH / THT, BB);   // (8,16,16) = 2048 blocks
    dim3 block(256);
    _Float16* bufs[2] = {h0, h1};
    // step t reads bufs[t&1], writes bufs[(t+1)&1]
    lstm_step<0><<<grid, block, 0, stream>>>(x, 0, blob, bias, h0, bufs[1], cbuf,
                                             gamma, beta, mean, var, dw, db, out);
    for (int t = 1; t < TT - 1; ++t)
        lstm_step<1><<<grid, block, 0, stream>>>(x, t, blob, bias, bufs[t & 1],
                                                 bufs[(t + 1) & 1], cbuf,
                                                 gamma, beta, mean, var, dw, db, out);
    lstm_step<2><<<grid, block, 0, stream>>>(x, TT - 1, blob, bias, bufs[(TT - 1) & 1],
                                             nullptr, cbuf,
                                             gamma, beta, mean, var, dw, db, out);
}